// Round 3
// baseline (1267.222 us; speedup 1.0000x reference)
//
#include <hip/hip_runtime.h>
#include <hip/hip_fp16.h>

#define BB 16
#define TT 4096
#define TSZ 64
#define DE 128
#define HH 256
#define LDIM 512
#define ODIM 10
#define NBLKS 6
#define EPSF 1e-5f
#define CL 32
#define NC (TT/CL)        // 128 chunks
#define NROWS (BB*TT)     // 65536

typedef _Float16 f16x8 __attribute__((ext_vector_type(8)));
typedef float f32x4 __attribute__((ext_vector_type(4)));
#define MFMA16(a,b,c) __builtin_amdgcn_mfma_f32_16x16x32_f16((a),(b),(c),0,0,0)

// ---- f16 weight region layout (offsets in halfs, base = ws + WOFF_W16) ----
enum : size_t {
  HOFF_BG = 0,                                  // [NBLK][512][128]  (gamma*B, re|im rows)
  HOFF_WC = HOFF_BG + (size_t)NBLKS*512*128,    // [NBLK][128][512]  (C-proj, [d][hc])
  HOFF_W1 = HOFF_WC + (size_t)NBLKS*128*512,    // [NBLK][512][128]  (W1^T [l][d])
  HOFF_W2 = HOFF_W1 + (size_t)NBLKS*512*128,    // [NBLK][128][256]  (W2^T [d][g])
  HOFF_WE = HOFF_W2 + (size_t)NBLKS*128*256,    // [128][64]         (Wenc^T [d][k])
  HTOT_HALFS = HOFF_WE + 128*64
};

// ---- workspace layout (float offsets) ----
enum : size_t {
  WOFF_Y     = 0,                                   // [B*T*DE] encoder output
  WOFF_H     = WOFF_Y + (size_t)NROWS*DE,           // [B*T*DE] running hidden
  WOFF_W16   = WOFF_H + (size_t)NROWS*DE,           // f16 weights region
  WOFF_LAM   = WOFF_W16 + (HTOT_HALFS+1)/2,         // [NBLK][H][2]
  WOFF_LAML  = WOFF_LAM + (size_t)NBLKS*HH*2,       // [NBLK][H][2] lam^CL
  WOFF_POW   = WOFF_LAML + (size_t)NBLKS*HH*2,      // [NBLK][CL][H][2] lam^(CL-1-t)
  WOFF_SL    = WOFF_POW + (size_t)NBLKS*CL*HH*2,    // [B][NC][H][2]
  WOFF_CARRY = WOFF_SL + (size_t)BB*NC*HH*2,        // [B][NC][H][2]
  WOFF_STATS = WOFF_CARRY + (size_t)BB*NC*HH*2,     // [NBLK+1][2][DE]
  WOFF_POOL  = WOFF_STATS + (size_t)(NBLKS+1)*2*DE, // [B][DE]
  WS_FLOATS  = WOFF_POOL + (size_t)BB*DE
};

// ---- dynamic LDS layout (bytes) for k_block ----
#define SOFF_AC  0                          // f32 a[128], c[128]
#define SOFF_DV  1024                       // f32 [128]
#define SOFF_U   1536                       // half [32][136]
#define SOFF_YL  (SOFF_U + CL*136*2)        // half [32][136] / MODE0 scratch f32[256][2]
#define SOFF_HT  (SOFF_YL + CL*136*2)       // half [32][520]
#define SOFF_G   SOFF_U                     // half [32][264] overlays U+YL
#define SMEM_SZ  (SOFF_HT + CL*520*2)       // 52224 B -> 3 wg/CU

// ============================ prep: lam + pow table + f16 weight repack ============================
__global__ __launch_bounds__(256) void k_prep(
    const float* __restrict__ nu_log, const float* __restrict__ theta_log,
    const float* __restrict__ B_re, const float* __restrict__ B_im,
    const float* __restrict__ C_re, const float* __restrict__ C_im,
    const float* __restrict__ W1g, const float* __restrict__ W2g,
    const float* __restrict__ Wenc, float* ws)
{
  const int i = blockIdx.x, h = threadIdx.x;
  __half* w16 = (__half*)(ws + WOFF_W16);
  const float nu  = expf(nu_log[i*HH+h]);
  const float th  = expf(theta_log[i*HH+h]);
  const float mod = expf(-nu);
  const float lr = mod*cosf(th), li = mod*sinf(th);
  const float gamma = sqrtf(fmaxf(1.0f - mod*mod, 1e-8f));
  ws[WOFF_LAM + ((size_t)i*HH+h)*2+0] = lr;
  ws[WOFF_LAM + ((size_t)i*HH+h)*2+1] = li;
  // lam^CL (CL=32 -> 5 squarings)
  float ar = lr, ai = li;
  #pragma unroll
  for (int q = 0; q < 5; q++) { float nr = ar*ar - ai*ai, ni = 2.0f*ar*ai; ar = nr; ai = ni; }
  ws[WOFF_LAML + ((size_t)i*HH+h)*2+0] = ar;
  ws[WOFF_LAML + ((size_t)i*HH+h)*2+1] = ai;
  // pow[t] = lam^(CL-1-t)
  {
    float pr = 1.0f, pi = 0.0f;
    for (int j = 0; j < CL; j++) {
      const int t = CL-1-j;
      ws[WOFF_POW + (((size_t)i*CL + t)*HH + h)*2 + 0] = pr;
      ws[WOFF_POW + (((size_t)i*CL + t)*HH + h)*2 + 1] = pi;
      const float nr = pr*lr - pi*li, ni = pr*li + pi*lr;
      pr = nr; pi = ni;
    }
  }
  // BG [512][128]
  {
    __half* bg = w16 + HOFF_BG + (size_t)i*512*128;
    const float* bre = B_re + ((size_t)i*HH+h)*DE;
    const float* bim = B_im + ((size_t)i*HH+h)*DE;
    for (int d = 0; d < DE; d++) {
      bg[(size_t)h*128 + d]       = __float2half(bre[d]*gamma);
      bg[(size_t)(256+h)*128 + d] = __float2half(bim[d]*gamma);
    }
  }
  // WC [128][512]
  {
    __half* wc = w16 + HOFF_WC + (size_t)i*128*512;
    const float* cre = C_re + (size_t)i*DE*HH;
    const float* cim = C_im + (size_t)i*DE*HH;
    for (int d = 0; d < DE; d++) {
      wc[(size_t)d*512 + h]       = __float2half( cre[(size_t)d*HH + h]);
      wc[(size_t)d*512 + 256 + h] = __float2half(-cim[(size_t)d*HH + h]);
    }
  }
  // W1T [512][128]
  {
    __half* w1t = w16 + HOFF_W1 + (size_t)i*512*128;
    for (int d = 0; d < DE; d++) {
      w1t[(size_t)h*128 + d]       = __float2half(W1g[((size_t)i*DE + d)*LDIM + h]);
      w1t[(size_t)(256+h)*128 + d] = __float2half(W1g[((size_t)i*DE + d)*LDIM + 256 + h]);
    }
  }
  // W2T [128][256]
  if (h < 128) {
    __half* w2t = w16 + HOFF_W2 + (size_t)i*128*256;
    for (int g = 0; g < 256; g++)
      w2t[(size_t)h*256 + g] = __float2half(W2g[((size_t)i*256 + g)*DE + h]);
  }
  // WencT [128][64]
  if (i == 0 && h < 128) {
    __half* wet = w16 + HOFF_WE;
    for (int k = 0; k < TSZ; k++)
      wet[(size_t)h*TSZ + k] = __float2half(Wenc[(size_t)k*DE + h]);
  }
}

// ============================ encoder (MFMA, 64-row tiles) ============================
__global__ __launch_bounds__(512) void k_enc(
    const float* __restrict__ x, const float* __restrict__ benc, float* ws)
{
  __shared__ __half XT[64*72];
  const int tid = threadIdx.x, w = tid >> 6, l = tid & 63;
  const size_t row0 = (size_t)blockIdx.x * 64;
  {
    const float4* xg = (const float4*)(x + row0*TSZ);
    for (int idx = tid; idx < 1024; idx += 512) {
      float4 v = xg[idx];
      const int r = idx >> 4, c4 = (idx & 15)*4;
      *(__half2*)&XT[r*72 + c4]     = __half2{__float2half(v.x), __float2half(v.y)};
      *(__half2*)&XT[r*72 + c4 + 2] = __half2{__float2half(v.z), __float2half(v.w)};
    }
  }
  __syncthreads();
  const __half* wet = (const __half*)(ws + WOFF_W16) + HOFF_WE;
  const int n0 = w*16;
  f32x4 acc[4];
  #pragma unroll
  for (int mt = 0; mt < 4; mt++) acc[mt] = (f32x4)(0.0f);
  #pragma unroll
  for (int k0 = 0; k0 < 64; k0 += 32) {
    f16x8 bf = *(const f16x8*)&wet[(size_t)(n0 + (l&15))*64 + k0 + (l>>4)*8];
    #pragma unroll
    for (int mt = 0; mt < 4; mt++) {
      f16x8 af = *(const f16x8*)&XT[(mt*16 + (l&15))*72 + k0 + (l>>4)*8];
      acc[mt] = MFMA16(af, bf, acc[mt]);
    }
  }
  const int d = n0 + (l&15);
  const float be = benc[d];
  float s = 0.0f, ss = 0.0f;
  float* y = ws + WOFF_Y;
  #pragma unroll
  for (int mt = 0; mt < 4; mt++)
    #pragma unroll
    for (int j = 0; j < 4; j++) {
      const int t = mt*16 + (l>>4)*4 + j;
      const float v = acc[mt][j] + be;
      y[(row0 + t)*DE + d] = v;
      s += v; ss += v*v;
    }
  s  += __shfl_xor(s, 16);  s  += __shfl_xor(s, 32);
  ss += __shfl_xor(ss, 16); ss += __shfl_xor(ss, 32);
  if (l < 16) {
    atomicAdd(ws + WOFF_STATS + d, s);
    atomicAdd(ws + WOFF_STATS + DE + d, ss);
  }
}

// ============================ carry composition across chunks ============================
__global__ void k_carry(float* ws, int i)
{
  const int h = threadIdx.x;   // 256
  const int b = blockIdx.x;    // 16
  const float Lr = ws[WOFF_LAML + ((size_t)i*HH+h)*2+0];
  const float Li = ws[WOFF_LAML + ((size_t)i*HH+h)*2+1];
  float sr = 0.0f, si = 0.0f;
  ws[WOFF_CARRY + ((size_t)(b*NC+0)*HH + h)*2+0] = 0.0f;
  ws[WOFF_CARRY + ((size_t)(b*NC+0)*HH + h)*2+1] = 0.0f;
  for (int c = 1; c < NC; c++) {
    const float pr = ws[WOFF_SL + ((size_t)(b*NC + c-1)*HH + h)*2+0];
    const float pi = ws[WOFF_SL + ((size_t)(b*NC + c-1)*HH + h)*2+1];
    const float nr = Lr*sr - Li*si + pr;
    const float ni = Lr*si + Li*sr + pi;
    sr = nr; si = ni;
    ws[WOFF_CARRY + ((size_t)(b*NC+c)*HH + h)*2+0] = sr;
    ws[WOFF_CARRY + ((size_t)(b*NC+c)*HH + h)*2+1] = si;
  }
}

// ============================ main fused block kernel (MFMA) ============================
// MODE 0: BN + B-proj + parallel weighted-sum -> SL
// MODE 1: BN + B-proj + scan(carry) + C-proj + MLP + residual + stats
template<int MODE>
__global__ __launch_bounds__(512, 6) void k_block(
    const float* hin, float* ws,
    const float* __restrict__ bnsg, const float* __restrict__ bnbg,
    const float* __restrict__ b1g, const float* __restrict__ b2g,
    const float* __restrict__ Dvg, int iblk, int islast)
{
  extern __shared__ char smem[];
  float* AC  = (float*)(smem + SOFF_AC);
  float* DVs = (float*)(smem + SOFF_DV);
  __half* U  = (__half*)(smem + SOFF_U);
  __half* YL = (__half*)(smem + SOFF_YL);
  __half* G  = (__half*)(smem + SOFF_G);
  __half* HT = (__half*)(smem + SOFF_HT);
  const __half* w16 = (const __half*)(ws + WOFF_W16);
  const int tid = threadIdx.x, w = tid >> 6, l = tid & 63;
  const int b = blockIdx.y, cb = blockIdx.x;
  const int row0 = b*TT + cb*CL;

  // BN coefs computed in-kernel (redundant per wg) from global stats
  if (tid < DE) {
    const float inv = 1.0f / (float)NROWS;
    const float s  = ws[WOFF_STATS + ((size_t)iblk*2+0)*DE + tid];
    const float sq = ws[WOFF_STATS + ((size_t)iblk*2+1)*DE + tid];
    const float mean = s*inv;
    const float var  = sq*inv - mean*mean;
    const float rstd = rsqrtf(var + EPSF);
    const float a = rstd * bnsg[iblk*DE + tid];
    AC[tid]      = a;
    AC[DE + tid] = bnbg[iblk*DE + tid] - mean*a;
    if (MODE == 1) DVs[tid] = Dvg[iblk*DE + tid];
  }
  __syncthreads();
  // P0: load h tile, BN -> U (f16, stride 136)
  {
    const float4* hg = (const float4*)(hin + (size_t)row0*DE);
    #pragma unroll
    for (int it = 0; it < 2; it++) {
      const int idx = tid + it*512;
      float4 v = hg[idx];
      const int row = idx >> 5, d0 = (idx & 31)*4;
      const float v0 = v.x*AC[d0+0] + AC[DE+d0+0];
      const float v1 = v.y*AC[d0+1] + AC[DE+d0+1];
      const float v2 = v.z*AC[d0+2] + AC[DE+d0+2];
      const float v3 = v.w*AC[d0+3] + AC[DE+d0+3];
      *(__half2*)&U[row*136 + d0]     = __half2{__float2half(v0), __float2half(v1)};
      *(__half2*)&U[row*136 + d0 + 2] = __half2{__float2half(v2), __float2half(v3)};
    }
  }
  __syncthreads();
  // P1: Bu = U @ BG^T -> HT [32][520]  (M=32,N=512,K=128); wave: all M, N=64
  {
    const __half* BG = w16 + HOFF_BG + (size_t)iblk*512*128;
    const int n0 = w*64;
    f32x4 acc[2][4];
    #pragma unroll
    for (int mt = 0; mt < 2; mt++)
      #pragma unroll
      for (int nt = 0; nt < 4; nt++) acc[mt][nt] = (f32x4)(0.0f);
    #pragma unroll
    for (int k0 = 0; k0 < 128; k0 += 32) {
      f16x8 af[2], bf[4];
      #pragma unroll
      for (int mt = 0; mt < 2; mt++)
        af[mt] = *(const f16x8*)&U[(mt*16 + (l&15))*136 + k0 + (l>>4)*8];
      #pragma unroll
      for (int nt = 0; nt < 4; nt++)
        bf[nt] = *(const f16x8*)&BG[(size_t)(n0 + nt*16 + (l&15))*128 + k0 + (l>>4)*8];
      #pragma unroll
      for (int mt = 0; mt < 2; mt++)
        #pragma unroll
        for (int nt = 0; nt < 4; nt++)
          acc[mt][nt] = MFMA16(af[mt], bf[nt], acc[mt][nt]);
    }
    #pragma unroll
    for (int mt = 0; mt < 2; mt++)
      #pragma unroll
      for (int nt = 0; nt < 4; nt++)
        #pragma unroll
        for (int j = 0; j < 4; j++)
          HT[(mt*16 + (l>>4)*4 + j)*520 + n0 + nt*16 + (l&15)] = __float2half(acc[mt][nt][j]);
  }
  __syncthreads();

  if (MODE == 0) {
    // parallel weighted sum: s_final[h] = sum_t lam^(CL-1-t) * Bu[t][h]
    const float* powp = ws + WOFF_POW + (size_t)iblk*CL*HH*2;
    float* SC = (float*)(smem + SOFF_YL);   // scratch [256][2] f32
    const int h = tid & 255, half = tid >> 8;
    float sr = 0.0f, si = 0.0f;
    #pragma unroll
    for (int j = 0; j < 16; j++) {
      const int t = half*16 + j;
      const float br = __half2float(HT[t*520 + h]);
      const float bi = __half2float(HT[t*520 + 256 + h]);
      const float2 p = *(const float2*)&powp[((size_t)t*HH + h)*2];
      sr += p.x*br - p.y*bi;
      si += p.x*bi + p.y*br;
    }
    if (half) { SC[h*2] = sr; SC[h*2+1] = si; }
    __syncthreads();
    if (!half) {
      sr += SC[h*2]; si += SC[h*2+1];
      ws[WOFF_SL + ((size_t)(b*NC+cb)*HH + h)*2+0] = sr;
      ws[WOFF_SL + ((size_t)(b*NC+cb)*HH + h)*2+1] = si;
    }
    return;
  }

  // P2: sequential scan over 32 t (threads 0..255 own channel h)
  if (tid < HH) {
    const int h = tid;
    const float lr = ws[WOFF_LAM + ((size_t)iblk*HH+h)*2+0];
    const float li = ws[WOFF_LAM + ((size_t)iblk*HH+h)*2+1];
    float sr = ws[WOFF_CARRY + ((size_t)(b*NC+cb)*HH + h)*2+0];
    float si = ws[WOFF_CARRY + ((size_t)(b*NC+cb)*HH + h)*2+1];
    for (int t = 0; t < CL; t++) {
      const float br = __half2float(HT[t*520 + h]);
      const float bi = __half2float(HT[t*520 + 256 + h]);
      const float nr = lr*sr - li*si + br;
      const float ni = lr*si + li*sr + bi;
      sr = nr; si = ni;
      HT[t*520 + h]       = __float2half(sr);
      HT[t*520 + 256 + h] = __float2half(si);
    }
  }
  __syncthreads();
  // P3: ylru = Re(C h) + u*D  (M=32,N=128,K=512); wave: all M, N=16
  {
    const __half* WC = w16 + HOFF_WC + (size_t)iblk*128*512;
    const int n0 = w*16;
    f32x4 acc[2];
    #pragma unroll
    for (int mt = 0; mt < 2; mt++) acc[mt] = (f32x4)(0.0f);
    #pragma unroll
    for (int k0 = 0; k0 < 512; k0 += 32) {
      f16x8 bf = *(const f16x8*)&WC[(size_t)(n0 + (l&15))*512 + k0 + (l>>4)*8];
      #pragma unroll
      for (int mt = 0; mt < 2; mt++) {
        f16x8 af = *(const f16x8*)&HT[(mt*16 + (l&15))*520 + k0 + (l>>4)*8];
        acc[mt] = MFMA16(af, bf, acc[mt]);
      }
    }
    const int d = n0 + (l&15);
    const float dv = DVs[d];
    #pragma unroll
    for (int mt = 0; mt < 2; mt++)
      #pragma unroll
      for (int j = 0; j < 4; j++) {
        const int t = mt*16 + (l>>4)*4 + j;
        const float v = acc[mt][j] + __half2float(U[t*136 + d])*dv;
        YL[t*136 + d] = __float2half(v);
      }
  }
  __syncthreads();
  // P4: Z1 = YL @ W1 + b1 -> HT  (M=32,N=512,K=128); wave: all M, N=64
  {
    const __half* W1T = w16 + HOFF_W1 + (size_t)iblk*512*128;
    const int n0 = w*64;
    f32x4 acc[2][4];
    #pragma unroll
    for (int mt = 0; mt < 2; mt++)
      #pragma unroll
      for (int nt = 0; nt < 4; nt++) acc[mt][nt] = (f32x4)(0.0f);
    #pragma unroll
    for (int k0 = 0; k0 < 128; k0 += 32) {
      f16x8 af[2], bf[4];
      #pragma unroll
      for (int mt = 0; mt < 2; mt++)
        af[mt] = *(const f16x8*)&YL[(mt*16 + (l&15))*136 + k0 + (l>>4)*8];
      #pragma unroll
      for (int nt = 0; nt < 4; nt++)
        bf[nt] = *(const f16x8*)&W1T[(size_t)(n0 + nt*16 + (l&15))*128 + k0 + (l>>4)*8];
      #pragma unroll
      for (int mt = 0; mt < 2; mt++)
        #pragma unroll
        for (int nt = 0; nt < 4; nt++)
          acc[mt][nt] = MFMA16(af[mt], bf[nt], acc[mt][nt]);
    }
    #pragma unroll
    for (int nt = 0; nt < 4; nt++) {
      const int col = n0 + nt*16 + (l&15);
      const float bb = b1g[(size_t)iblk*LDIM + col];
      #pragma unroll
      for (int mt = 0; mt < 2; mt++)
        #pragma unroll
        for (int j = 0; j < 4; j++)
          HT[(mt*16 + (l>>4)*4 + j)*520 + col] = __float2half(acc[mt][nt][j] + bb);
    }
  }
  __syncthreads();
  // P5: GLU -> G [32][264]
  #pragma unroll
  for (int it = 0; it < 16; it++) {
    const int idx = tid + it*512;
    const int t = idx >> 8, j = idx & 255;
    const float av = __half2float(HT[t*520 + j]);
    const float bv = __half2float(HT[t*520 + 256 + j]);
    G[t*264 + j] = __float2half(av / (1.0f + __expf(-bv)));
  }
  __syncthreads();
  // P6: h_new = G @ W2 + b2 + y  (M=32,N=128,K=256); wave: all M, N=16
  {
    const __half* W2T = w16 + HOFF_W2 + (size_t)iblk*128*256;
    const int n0 = w*16;
    const int d = n0 + (l&15);
    f32x4 acc[2];
    #pragma unroll
    for (int mt = 0; mt < 2; mt++) acc[mt] = (f32x4)(0.0f);
    #pragma unroll
    for (int k0 = 0; k0 < 256; k0 += 32) {
      f16x8 bf = *(const f16x8*)&W2T[(size_t)d*256 + k0 + (l>>4)*8];
      #pragma unroll
      for (int mt = 0; mt < 2; mt++) {
        f16x8 af = *(const f16x8*)&G[(mt*16 + (l&15))*264 + k0 + (l>>4)*8];
        acc[mt] = MFMA16(af, bf, acc[mt]);
      }
    }
    const float bb = b2g[(size_t)iblk*DE + d];
    float s = 0.0f, ss = 0.0f;
    #pragma unroll
    for (int mt = 0; mt < 2; mt++)
      #pragma unroll
      for (int j = 0; j < 4; j++) {
        const int t = mt*16 + (l>>4)*4 + j;
        const size_t row = (size_t)(row0 + t);
        const float v = acc[mt][j] + bb + ws[WOFF_Y + row*DE + d];
        ws[WOFF_H + row*DE + d] = v;
        s += v; ss += v*v;
      }
    s  += __shfl_xor(s, 16);  s  += __shfl_xor(s, 32);
    ss += __shfl_xor(ss, 16); ss += __shfl_xor(ss, 32);
    if (l < 16) {
      atomicAdd(ws + WOFF_STATS + (size_t)((iblk+1)*2 + 0)*DE + d, s);
      atomicAdd(ws + WOFF_STATS + (size_t)((iblk+1)*2 + 1)*DE + d, ss);
      if (islast) atomicAdd(ws + WOFF_POOL + (size_t)b*DE + d, s);
    }
  }
}

// ============================ final projection ============================
__global__ void k_out(const float* __restrict__ Wout, const float* __restrict__ bout,
                      const float* __restrict__ ws, float* __restrict__ out)
{
  const int tid = threadIdx.x;
  if (tid < BB*ODIM) {
    const int b = tid / ODIM, o = tid % ODIM;
    float acc = bout[o];
    const float* p = ws + WOFF_POOL + (size_t)b*DE;
    const float invT = 1.0f / (float)TT;
    for (int d = 0; d < DE; d++) acc += p[d]*invT*Wout[d*ODIM + o];
    out[tid] = acc;
  }
}

extern "C" void kernel_launch(void* const* d_in, const int* in_sizes, int n_in,
                              void* d_out, int out_size, void* d_ws, size_t ws_size,
                              hipStream_t stream)
{
  const float* x   = (const float*)d_in[0];
  const float* nu  = (const float*)d_in[1];
  const float* th  = (const float*)d_in[2];
  const float* Bre = (const float*)d_in[3];
  const float* Bim = (const float*)d_in[4];
  const float* Cre = (const float*)d_in[5];
  const float* Cim = (const float*)d_in[6];
  const float* Dv  = (const float*)d_in[7];
  const float* W1  = (const float*)d_in[8];
  const float* b1  = (const float*)d_in[9];
  const float* W2  = (const float*)d_in[10];
  const float* b2  = (const float*)d_in[11];
  const float* bns = (const float*)d_in[12];
  const float* bnb = (const float*)d_in[13];
  const float* We  = (const float*)d_in[14];
  const float* be  = (const float*)d_in[15];
  const float* Wo  = (const float*)d_in[16];
  const float* bo  = (const float*)d_in[17];
  float* ws = (float*)d_ws;
  float* out = (float*)d_out;

  (void)hipFuncSetAttribute((const void*)k_block<0>,
        hipFuncAttributeMaxDynamicSharedMemorySize, SMEM_SZ);
  (void)hipFuncSetAttribute((const void*)k_block<1>,
        hipFuncAttributeMaxDynamicSharedMemorySize, SMEM_SZ);

  hipMemsetAsync(ws + WOFF_STATS, 0,
                 (size_t)(((NBLKS+1)*2*DE) + BB*DE)*sizeof(float), stream);

  k_prep<<<NBLKS, 256, 0, stream>>>(nu, th, Bre, Bim, Cre, Cim, W1, W2, We, ws);
  k_enc<<<NROWS/64, 512, 0, stream>>>(x, be, ws);

  for (int i = 0; i < NBLKS; i++) {
    const float* hin = (i == 0) ? (ws + WOFF_Y) : (ws + WOFF_H);
    k_block<0><<<dim3(NC, BB), 512, SMEM_SZ, stream>>>(hin, ws, bns, bnb, b1, b2, Dv, i, 0);
    k_carry<<<BB, 256, 0, stream>>>(ws, i);
    k_block<1><<<dim3(NC, BB), 512, SMEM_SZ, stream>>>(hin, ws, bns, bnb, b1, b2, Dv, i,
                                                       (i == NBLKS-1) ? 1 : 0);
  }
  k_out<<<1, 256, 0, stream>>>(Wo, bo, ws, out);
}